// Round 7
// baseline (1309.897 us; speedup 1.0000x reference)
//
#include <hip/hip_runtime.h>

#define N_NODES 50000
#define N_EDGES 800000
#define HROW 72   // u16 row stride for LDS H tiles

typedef unsigned short u16;
typedef __attribute__((ext_vector_type(8))) short short8;
typedef __attribute__((ext_vector_type(4))) float f32x4;

#define MFMA16(a, b, c) __builtin_amdgcn_mfma_f32_16x16x32_bf16((a), (b), (c), 0, 0, 0)

__device__ __forceinline__ float b2f(u16 u) {
    union { unsigned int i; float f; } v; v.i = ((unsigned int)u) << 16; return v.f;
}
__device__ __forceinline__ u16 f2b(float f) {
    union { float f; unsigned int i; } v; v.f = f;
    unsigned int x = v.i;
    return (u16)((x + 0x7fffu + ((x >> 16) & 1u)) >> 16);
}
__device__ __forceinline__ short8 cvt8(const float* p) {
    const float4 a = *(const float4*)p;
    const float4 b = *(const float4*)(p + 4);
    short8 r;
    r[0] = (short)f2b(a.x); r[1] = (short)f2b(a.y); r[2] = (short)f2b(a.z); r[3] = (short)f2b(a.w);
    r[4] = (short)f2b(b.x); r[5] = (short)f2b(b.y); r[6] = (short)f2b(b.z); r[7] = (short)f2b(b.w);
    return r;
}

// ---- fp32 -> bf16 bulk convert ---------------------------------------------
__global__ void cvt_bf16(const float* __restrict__ in, u16* __restrict__ out, int n8) {
    const int i = blockIdx.x * 256 + threadIdx.x;
    if (i < n8) *(short8*)&out[i * 8] = cvt8(&in[i * 8]);
}

// ---- CSR build --------------------------------------------------------------
__global__ void csr_hist(const int* __restrict__ dst, int* __restrict__ deg) {
    const int e = blockIdx.x * 256 + threadIdx.x;
    if (e < N_EDGES) atomicAdd(&deg[dst[e]], 1);
}
__global__ void csr_scan(const int* __restrict__ deg, int* __restrict__ off,
                         int* __restrict__ cur) {
    __shared__ int tot[1024];
    const int t = threadIdx.x;
    const int beg = t * 49;
    const int end = (beg + 49 < N_NODES) ? beg + 49 : N_NODES;
    int s = 0;
    for (int i = beg; i < end; ++i) s += deg[i];
    tot[t] = s;
    __syncthreads();
    for (int d = 1; d < 1024; d <<= 1) {
        const int v = (t >= d) ? tot[t - d] : 0;
        __syncthreads();
        tot[t] += v;
        __syncthreads();
    }
    int run = tot[t] - s;
    for (int i = beg; i < end; ++i) { off[i] = run; cur[i] = run; run += deg[i]; }
    if (t == 1023) off[N_NODES] = tot[1023];
}
__global__ void csr_scatter(const int* __restrict__ src, const int* __restrict__ dst,
                            int* __restrict__ cur, int* __restrict__ eidx,
                            int* __restrict__ ssrc, int* __restrict__ sdst) {
    const int e = blockIdx.x * 256 + threadIdx.x;
    if (e < N_EDGES) {
        const int d = dst[e];
        const int p = atomicAdd(&cur[d], 1);
        eidx[p] = e; ssrc[p] = src[e]; sdst[p] = d;
    }
}

// ---- one-shot weight swizzle (all layers, edge + node) into B-frag order ----
__global__ void swizzle_all(const float* __restrict__ eW0, const float* __restrict__ eW1,
                            const float* __restrict__ eW2, const float* __restrict__ eW3,
                            const float* __restrict__ nW0, const float* __restrict__ nW1,
                            const float* __restrict__ nW2, const float* __restrict__ nW3,
                            u16* __restrict__ eswz, u16* __restrict__ nswz)
{
    const int ETOT = 3 * 12 * 2048, NTOT = 3 * 10 * 2048;
    for (int idx = blockIdx.x * 256 + threadIdx.x; idx < ETOT + NTOT; idx += gridDim.x * 256) {
        const bool isE = idx < ETOT;
        const int id = isE ? idx : idx - ETOT;
        const int per = isE ? 12 * 2048 : 10 * 2048;
        const int l = id / per, rem = id % per;
        const int t = rem >> 11;
        const int r2 = rem & 2047;
        const int nt = r2 >> 9, lane = (r2 >> 3) & 63, j = r2 & 7;
        const int ks0 = isE ? 6 : 4;
        const float* W; int ks;
        if (t < ks0) {
            W = (isE ? eW0 : nW0) + (size_t)l * (isE ? 192 * 64 : 128 * 64);
            ks = t;
        } else {
            const int u = t - ks0;
            const float* Wb = isE ? (u < 2 ? eW1 : (u < 4 ? eW2 : eW3))
                                  : (u < 2 ? nW1 : (u < 4 ? nW2 : nW3));
            W = Wb + (size_t)l * 4096; ks = u & 1;
        }
        const int k = ks * 32 + (lane >> 4) * 8 + j;
        const int n = nt * 16 + (lane & 15);
        const u16 v = f2b(W[k * 64 + n]);
        if (isE) eswz[id] = v; else nswz[id] = v;
    }
}

// ===================== edge pass (sorted stream, MFMA, nt + idx prefetch) ====
__global__ __launch_bounds__(512, 4)
void edge_pass(const u16* __restrict__ h16,
               const float* __restrict__ e32,      // fp32 edge feats (layer0) or null
               const int* __restrict__ eidx,       // sorted->orig perm (layer0)
               u16* __restrict__ e_sorted,         // bf16 state, in-place (layers 1,2)
               const int* __restrict__ ssrc, const int* __restrict__ sdst,
               const u16* __restrict__ wz,
               const float* __restrict__ b0, const float* __restrict__ b1,
               const float* __restrict__ b2, const float* __restrict__ b3)
{
    __shared__ u16 w0s[6 * 2048];      // 24 KB
    __shared__ u16 w1s[3 * 2 * 2048];  // 24 KB
    __shared__ float biasS[256];
    __shared__ u16 hb[8 * 16 * HROW];  // 18 KB

    const int tid = threadIdx.x;
    {
        const uint4* s = (const uint4*)wz;
        uint4* dA = (uint4*)w0s; uint4* dB = (uint4*)w1s;
        #pragma unroll
        for (int i = 0; i < 3; ++i) dA[tid + i * 512] = s[tid + i * 512];
        #pragma unroll
        for (int i = 0; i < 3; ++i) dB[tid + i * 512] = s[1536 + tid + i * 512];
        if (tid < 256) {
            const int which = tid >> 6, j = tid & 63;
            const float* bp = (which == 0) ? b0 : (which == 1) ? b1 : (which == 2) ? b2 : b3;
            biasS[tid] = bp[j];
        }
    }
    __syncthreads();  // only barrier

    const int w = tid >> 6, lane = tid & 63, col = lane & 15, q = lane >> 4;
    u16* hw = &hb[w * 16 * HROW];
    const int nT = N_EDGES / 128;
    const int G = gridDim.x;
    const bool ef = (e32 != nullptr);

    // prologue: indices for first tile
    int t = blockIdx.x;
    int jm = t * 128 + w * 16 + col;
    int sv = ssrc[jm], tv = sdst[jm];
    int ei = ef ? eidx[jm] : 0;

    for (; t < nT; ) {
        // issue this tile's fragment gathers (6 independent 16B loads)
        short8 af[6];
        af[0] = *(const short8*)&h16[(size_t)sv * 64 + q * 8];
        af[1] = *(const short8*)&h16[(size_t)sv * 64 + 32 + q * 8];
        af[2] = *(const short8*)&h16[(size_t)tv * 64 + q * 8];
        af[3] = *(const short8*)&h16[(size_t)tv * 64 + 32 + q * 8];
        if (ef) {
            af[4] = cvt8(&e32[(size_t)ei * 64 + q * 8]);
            af[5] = cvt8(&e32[(size_t)ei * 64 + 32 + q * 8]);
        } else {
            af[4] = __builtin_nontemporal_load((const short8*)&e_sorted[(size_t)jm * 64 + q * 8]);
            af[5] = __builtin_nontemporal_load((const short8*)&e_sorted[(size_t)jm * 64 + 32 + q * 8]);
        }

        // prefetch NEXT tile's indices only (cheap; hides the idx->gather hop)
        const int tn = t + G;
        int svn = sv, tvn = tv, ein = ei, jn = jm;
        if (tn < nT) {
            jn = tn * 128 + w * 16 + col;
            svn = ssrc[jn]; tvn = sdst[jn];
            if (ef) ein = eidx[jn];
        }

        // ---- layer 1: K=192 ----
        #pragma unroll
        for (int nt = 0; nt < 4; ++nt) {
            f32x4 acc = {0.f, 0.f, 0.f, 0.f};
            #pragma unroll
            for (int ks = 0; ks < 6; ++ks)
                acc = MFMA16(af[ks], *(const short8*)&w0s[(ks * 4 + nt) * 512 + lane * 8], acc);
            const float bv = biasS[nt * 16 + col];
            #pragma unroll
            for (int r = 0; r < 4; ++r)
                hw[(q * 4 + r) * HROW + nt * 16 + col] = f2b(fmaxf(acc[r] + bv, 0.f));
        }
        // ---- layers 2..4: K=64 ----
        #pragma unroll
        for (int li = 0; li < 3; ++li) {
            const short8 ah0 = *(const short8*)&hw[col * HROW + q * 8];
            const short8 ah1 = *(const short8*)&hw[col * HROW + 32 + q * 8];
            const u16* wls = &w1s[li * 4096];
            #pragma unroll
            for (int nt = 0; nt < 4; ++nt) {
                f32x4 acc = {0.f, 0.f, 0.f, 0.f};
                acc = MFMA16(ah0, *(const short8*)&wls[nt * 512 + lane * 8], acc);
                acc = MFMA16(ah1, *(const short8*)&wls[(4 + nt) * 512 + lane * 8], acc);
                const float bv = biasS[(li + 1) * 64 + nt * 16 + col];
                #pragma unroll
                for (int r = 0; r < 4; ++r)
                    hw[(q * 4 + r) * HROW + nt * 16 + col] = f2b(fmaxf(acc[r] + bv, 0.f));
            }
        }
        // ---- coalesced non-temporal e_sorted store ----
        {
            const int erow = lane >> 2, echk = lane & 3;
            const short8 o0 = *(const short8*)&hw[erow * HROW + echk * 8];
            const short8 o1 = *(const short8*)&hw[erow * HROW + 32 + echk * 8];
            const size_t ebo = (size_t)(t * 128 + w * 16 + erow) * 64;
            __builtin_nontemporal_store(o0, (short8*)&e_sorted[ebo + echk * 8]);
            __builtin_nontemporal_store(o1, (short8*)&e_sorted[ebo + 32 + echk * 8]);
        }
        // rotate
        t = tn; jm = jn; sv = svn; tv = tvn; ei = ein;
    }
}

// ===================== node pass (contiguous CSR scan + MFMA MLP) ============
__global__ __launch_bounds__(512, 4)
void node_pass(const u16* __restrict__ e_sorted,
               const int* __restrict__ off,
               const u16* __restrict__ h16,
               const u16* __restrict__ wz,
               const float* __restrict__ b0, const float* __restrict__ b1,
               const float* __restrict__ b2, const float* __restrict__ b3,
               u16* __restrict__ hout16, float* __restrict__ hout32)
{
    __shared__ u16 w0s[4 * 2048];      // 16 KB
    __shared__ u16 w1s[3 * 2 * 2048];  // 24 KB
    __shared__ float biasS[256];
    __shared__ u16 hb[8 * 16 * HROW];

    const int tid = threadIdx.x;
    {
        const uint4* s = (const uint4*)wz;
        uint4* dA = (uint4*)w0s; uint4* dB = (uint4*)w1s;
        #pragma unroll
        for (int i = 0; i < 2; ++i) dA[tid + i * 512] = s[tid + i * 512];
        #pragma unroll
        for (int i = 0; i < 3; ++i) dB[tid + i * 512] = s[1024 + tid + i * 512];
        if (tid < 256) {
            const int which = tid >> 6, j = tid & 63;
            const float* bp = (which == 0) ? b0 : (which == 1) ? b1 : (which == 2) ? b2 : b3;
            biasS[tid] = bp[j];
        }
    }
    __syncthreads();

    const int w = tid >> 6, lane = tid & 63, col = lane & 15, q = lane >> 4;
    const int nd = lane >> 2, sub = lane & 3;   // 4 lanes per node, 16 cols each
    u16* hw = &hb[w * 16 * HROW];
    const int nTiles = (N_NODES + 127) / 128;

    for (int tile = blockIdx.x; tile < nTiles; tile += gridDim.x) {
        const int base = tile * 128 + w * 16;

        // ---- aggregation: contiguous rows off[n]..off[n+1), fp32 regs ----
        float acc[16];
        #pragma unroll
        for (int i = 0; i < 16; ++i) acc[i] = 0.f;
        const int node = base + nd;
        if (node < N_NODES) {
            int j = off[node];
            const int j1 = off[node + 1];
            for (; j + 4 <= j1; j += 4) {  // 8 nt loads in flight
                const u16* p = &e_sorted[(size_t)j * 64 + sub * 16];
                short8 a0 = __builtin_nontemporal_load((const short8*)p);
                short8 c0 = __builtin_nontemporal_load((const short8*)(p + 8));
                short8 a1 = __builtin_nontemporal_load((const short8*)(p + 64));
                short8 c1 = __builtin_nontemporal_load((const short8*)(p + 72));
                short8 a2 = __builtin_nontemporal_load((const short8*)(p + 128));
                short8 c2 = __builtin_nontemporal_load((const short8*)(p + 136));
                short8 a3 = __builtin_nontemporal_load((const short8*)(p + 192));
                short8 c3 = __builtin_nontemporal_load((const short8*)(p + 200));
                #pragma unroll
                for (int x = 0; x < 8; ++x) {
                    acc[x]     += (b2f((u16)a0[x]) + b2f((u16)a1[x]))
                                + (b2f((u16)a2[x]) + b2f((u16)a3[x]));
                    acc[8 + x] += (b2f((u16)c0[x]) + b2f((u16)c1[x]))
                                + (b2f((u16)c2[x]) + b2f((u16)c3[x]));
                }
            }
            for (; j < j1; ++j) {
                const u16* p = &e_sorted[(size_t)j * 64 + sub * 16];
                short8 a = __builtin_nontemporal_load((const short8*)p);
                short8 c = __builtin_nontemporal_load((const short8*)(p + 8));
                #pragma unroll
                for (int x = 0; x < 8; ++x) {
                    acc[x] += b2f((u16)a[x]); acc[8 + x] += b2f((u16)c[x]);
                }
            }
        }
        // stage agg to LDS (bf16) row-major, then read A-frags
        {
            short8 p0, p1;
            #pragma unroll
            for (int i = 0; i < 8; ++i) { p0[i] = (short)f2b(acc[i]); p1[i] = (short)f2b(acc[8 + i]); }
            *(short8*)&hw[nd * HROW + sub * 16] = p0;
            *(short8*)&hw[nd * HROW + sub * 16 + 8] = p1;
        }
        short8 af[4];
        af[0] = *(const short8*)&hw[col * HROW + q * 8];
        af[1] = *(const short8*)&hw[col * HROW + 32 + q * 8];
        const int nm = base + col;
        const int nmc = (nm < N_NODES) ? nm : 0;
        af[2] = *(const short8*)&h16[(size_t)nmc * 64 + q * 8];
        af[3] = *(const short8*)&h16[(size_t)nmc * 64 + 32 + q * 8];

        // ---- layer 1: K=128 ----
        #pragma unroll
        for (int nt = 0; nt < 4; ++nt) {
            f32x4 c = {0.f, 0.f, 0.f, 0.f};
            #pragma unroll
            for (int ks = 0; ks < 4; ++ks)
                c = MFMA16(af[ks], *(const short8*)&w0s[(ks * 4 + nt) * 512 + lane * 8], c);
            const float bv = biasS[nt * 16 + col];
            #pragma unroll
            for (int r = 0; r < 4; ++r)
                hw[(q * 4 + r) * HROW + nt * 16 + col] = f2b(fmaxf(c[r] + bv, 0.f));
        }
        // ---- layers 2..4 ----
        #pragma unroll
        for (int li = 0; li < 3; ++li) {
            const short8 ah0 = *(const short8*)&hw[col * HROW + q * 8];
            const short8 ah1 = *(const short8*)&hw[col * HROW + 32 + q * 8];
            const u16* wls = &w1s[li * 4096];
            #pragma unroll
            for (int nt = 0; nt < 4; ++nt) {
                f32x4 c = {0.f, 0.f, 0.f, 0.f};
                c = MFMA16(ah0, *(const short8*)&wls[nt * 512 + lane * 8], c);
                c = MFMA16(ah1, *(const short8*)&wls[(4 + nt) * 512 + lane * 8], c);
                const float bv = biasS[(li + 1) * 64 + nt * 16 + col];
                #pragma unroll
                for (int r = 0; r < 4; ++r) {
                    const float v = fmaxf(c[r] + bv, 0.f);
                    if (li == 2 && hout32) {
                        const int row = base + q * 4 + r;
                        if (row < N_NODES) hout32[(size_t)row * 64 + nt * 16 + col] = v;
                    } else {
                        hw[(q * 4 + r) * HROW + nt * 16 + col] = f2b(v);
                    }
                }
            }
        }
        if (!hout32) {
            const int erow = lane >> 2, echk = lane & 3;
            const int row = base + erow;
            if (row < N_NODES) {
                const short8 o0 = *(const short8*)&hw[erow * HROW + echk * 8];
                const short8 o1 = *(const short8*)&hw[erow * HROW + 32 + echk * 8];
                *(short8*)&hout16[(size_t)row * 64 + echk * 8] = o0;
                *(short8*)&hout16[(size_t)row * 64 + 32 + echk * 8] = o1;
            }
        }
    }
}

extern "C" void kernel_launch(void* const* d_in, const int* in_sizes, int n_in,
                              void* d_out, int out_size, void* d_ws, size_t ws_size,
                              hipStream_t stream)
{
    const float* node_h = (const float*)d_in[0];
    const float* edge_h = (const float*)d_in[1];
    const int* src      = (const int*)d_in[2];
    const int* dst      = (const int*)d_in[3];
    const float* eW[4] = {(const float*)d_in[4],  (const float*)d_in[8],
                          (const float*)d_in[12], (const float*)d_in[16]};
    const float* eb[4] = {(const float*)d_in[5],  (const float*)d_in[9],
                          (const float*)d_in[13], (const float*)d_in[17]};
    const float* nW[4] = {(const float*)d_in[6],  (const float*)d_in[10],
                          (const float*)d_in[14], (const float*)d_in[18]};
    const float* nb[4] = {(const float*)d_in[7],  (const float*)d_in[11],
                          (const float*)d_in[15], (const float*)d_in[19]};

    // ws layout
    u16* ebuf = (u16*)d_ws;                              // e_sorted: 51.2M u16
    u16* hbuf = ebuf + (size_t)N_EDGES * 64;             // 3.2M u16
    u16* eswz = hbuf + (size_t)N_NODES * 64;             // 73728 u16
    u16* nswz = eswz + 3 * 24576;                        // 61440 u16
    int* off  = (int*)(nswz + 3 * 20480);                // N+1
    int* cur  = off + (N_NODES + 4);
    int* deg  = cur + N_NODES;
    int* eidx = deg + N_NODES;                           // E
    int* ssrc = eidx + N_EDGES;                          // E
    int* sdst = ssrc + N_EDGES;                          // E

    // one-time per launch
    cvt_bf16<<<(N_NODES * 64 / 8 + 255) / 256, 256, 0, stream>>>(node_h, hbuf, N_NODES * 64 / 8);
    hipMemsetAsync(deg, 0, N_NODES * sizeof(int), stream);
    csr_hist<<<(N_EDGES + 255) / 256, 256, 0, stream>>>(dst, deg);
    csr_scan<<<1, 1024, 0, stream>>>(deg, off, cur);
    csr_scatter<<<(N_EDGES + 255) / 256, 256, 0, stream>>>(src, dst, cur, eidx, ssrc, sdst);
    swizzle_all<<<528, 256, 0, stream>>>(eW[0], eW[1], eW[2], eW[3],
                                         nW[0], nW[1], nW[2], nW[3], eswz, nswz);

    for (int l = 0; l < 3; ++l) {
        edge_pass<<<512, 512, 0, stream>>>(
            hbuf, (l == 0) ? edge_h : nullptr, eidx, ebuf, ssrc, sdst,
            eswz + (size_t)l * 24576,
            eb[0] + l * 64, eb[1] + l * 64, eb[2] + l * 64, eb[3] + l * 64);
        node_pass<<<391, 512, 0, stream>>>(
            ebuf, off, hbuf, nswz + (size_t)l * 20480,
            nb[0] + l * 64, nb[1] + l * 64, nb[2] + l * 64, nb[3] + l * 64,
            (l < 2) ? hbuf : nullptr, (l == 2) ? (float*)d_out : nullptr);
    }
}

// Round 8
// 1194.295 us; speedup vs baseline: 1.0968x; 1.0968x over previous
//
#include <hip/hip_runtime.h>

#define N_NODES 50000
#define N_EDGES 800000
#define HROW 72   // u16 row stride for LDS H tiles

typedef unsigned short u16;
typedef __attribute__((ext_vector_type(8))) short short8;
typedef __attribute__((ext_vector_type(4))) float f32x4;

#define MFMA16(a, b, c) __builtin_amdgcn_mfma_f32_16x16x32_bf16((a), (b), (c), 0, 0, 0)

__device__ __forceinline__ float b2f(u16 u) {
    union { unsigned int i; float f; } v; v.i = ((unsigned int)u) << 16; return v.f;
}
__device__ __forceinline__ u16 f2b(float f) {
    union { float f; unsigned int i; } v; v.f = f;
    unsigned int x = v.i;
    return (u16)((x + 0x7fffu + ((x >> 16) & 1u)) >> 16);
}
__device__ __forceinline__ short8 cvt8(const float* p) {
    const float4 a = *(const float4*)p;
    const float4 b = *(const float4*)(p + 4);
    short8 r;
    r[0] = (short)f2b(a.x); r[1] = (short)f2b(a.y); r[2] = (short)f2b(a.z); r[3] = (short)f2b(a.w);
    r[4] = (short)f2b(b.x); r[5] = (short)f2b(b.y); r[6] = (short)f2b(b.z); r[7] = (short)f2b(b.w);
    return r;
}

// ---- fp32 -> bf16 bulk convert ---------------------------------------------
__global__ void cvt_bf16(const float* __restrict__ in, u16* __restrict__ out, int n8) {
    const int i = blockIdx.x * 256 + threadIdx.x;
    if (i < n8) *(short8*)&out[i * 8] = cvt8(&in[i * 8]);
}

// ---- CSR build --------------------------------------------------------------
__global__ void csr_hist(const int* __restrict__ dst, int* __restrict__ deg) {
    const int e = blockIdx.x * 256 + threadIdx.x;
    if (e < N_EDGES) atomicAdd(&deg[dst[e]], 1);
}
__global__ void csr_scan(const int* __restrict__ deg, int* __restrict__ off,
                         int* __restrict__ cur) {
    __shared__ int tot[1024];
    const int t = threadIdx.x;
    const int beg = t * 49;
    const int end = (beg + 49 < N_NODES) ? beg + 49 : N_NODES;
    int s = 0;
    for (int i = beg; i < end; ++i) s += deg[i];
    tot[t] = s;
    __syncthreads();
    for (int d = 1; d < 1024; d <<= 1) {
        const int v = (t >= d) ? tot[t - d] : 0;
        __syncthreads();
        tot[t] += v;
        __syncthreads();
    }
    int run = tot[t] - s;
    for (int i = beg; i < end; ++i) { const int d = deg[i]; off[i] = run; cur[i] = run; run += d; }
    if (t == 1023) off[N_NODES] = tot[1023];
}
__global__ void csr_scatter(const int* __restrict__ src, const int* __restrict__ dst,
                            int* __restrict__ cur, int* __restrict__ eidx,
                            int* __restrict__ ssrc, int* __restrict__ sdst) {
    const int e = blockIdx.x * 256 + threadIdx.x;
    if (e < N_EDGES) {
        const int d = dst[e];
        const int p = atomicAdd(&cur[d], 1);
        eidx[p] = e; ssrc[p] = src[e]; sdst[p] = d;
    }
}
// permute fp32 edge features into sorted bf16 rows
__global__ void perm_edge(const float* __restrict__ eh, const int* __restrict__ eidx,
                          u16* __restrict__ out) {
    const int idx = blockIdx.x * 256 + threadIdx.x;  // one thread per 8 cols
    if (idx < N_EDGES * 8) {
        const int j = idx >> 3, c = (idx & 7) * 8;
        const int e = eidx[j];
        *(short8*)&out[(size_t)j * 64 + c] = cvt8(&eh[(size_t)e * 64 + c]);
    }
}

// ---- one-shot weight swizzle (all layers, edge + node) into B-frag order ----
__global__ void swizzle_all(const float* __restrict__ eW0, const float* __restrict__ eW1,
                            const float* __restrict__ eW2, const float* __restrict__ eW3,
                            const float* __restrict__ nW0, const float* __restrict__ nW1,
                            const float* __restrict__ nW2, const float* __restrict__ nW3,
                            u16* __restrict__ eswz, u16* __restrict__ nswz)
{
    const int ETOT = 3 * 12 * 2048, NTOT = 3 * 10 * 2048;
    for (int idx = blockIdx.x * 256 + threadIdx.x; idx < ETOT + NTOT; idx += gridDim.x * 256) {
        const bool isE = idx < ETOT;
        const int id = isE ? idx : idx - ETOT;
        const int per = isE ? 12 * 2048 : 10 * 2048;
        const int l = id / per, rem = id % per;
        const int t = rem >> 11;
        const int r2 = rem & 2047;
        const int nt = r2 >> 9, lane = (r2 >> 3) & 63, j = r2 & 7;
        const int ks0 = isE ? 6 : 4;
        const float* W; int ks;
        if (t < ks0) {
            W = (isE ? eW0 : nW0) + (size_t)l * (isE ? 192 * 64 : 128 * 64);
            ks = t;
        } else {
            const int u = t - ks0;
            const float* Wb = isE ? (u < 2 ? eW1 : (u < 4 ? eW2 : eW3))
                                  : (u < 2 ? nW1 : (u < 4 ? nW2 : nW3));
            W = Wb + (size_t)l * 4096; ks = u & 1;
        }
        const int k = ks * 32 + (lane >> 4) * 8 + j;
        const int n = nt * 16 + (lane & 15);
        const u16 v = f2b(W[k * 64 + n]);
        if (isE) eswz[id] = v; else nswz[id] = v;
    }
}

// ===================== edge pass (sorted stream, MFMA) =======================
// 512 thr = 8 waves; wave owns 16 sorted-edge rows per tile of 128.
__global__ __launch_bounds__(512, 4)
void edge_pass(const u16* __restrict__ h16,
               u16* __restrict__ e_sorted,            // bf16 state, in-place
               const int* __restrict__ ssrc, const int* __restrict__ sdst,
               const u16* __restrict__ wz,
               const float* __restrict__ b0, const float* __restrict__ b1,
               const float* __restrict__ b2, const float* __restrict__ b3)
{
    __shared__ u16 w0s[6 * 2048];      // 24 KB
    __shared__ u16 w1s[3 * 2 * 2048];  // 24 KB
    __shared__ float biasS[256];
    __shared__ u16 hb[8 * 16 * HROW];  // 18 KB

    const int tid = threadIdx.x;
    {
        const uint4* s = (const uint4*)wz;
        uint4* dA = (uint4*)w0s; uint4* dB = (uint4*)w1s;
        #pragma unroll
        for (int i = 0; i < 3; ++i) dA[tid + i * 512] = s[tid + i * 512];
        #pragma unroll
        for (int i = 0; i < 3; ++i) dB[tid + i * 512] = s[1536 + tid + i * 512];
        if (tid < 256) {
            const int which = tid >> 6, j = tid & 63;
            const float* bp = (which == 0) ? b0 : (which == 1) ? b1 : (which == 2) ? b2 : b3;
            biasS[tid] = bp[j];
        }
    }
    __syncthreads();  // only barrier

    const int w = tid >> 6, lane = tid & 63, col = lane & 15, q = lane >> 4;
    u16* hw = &hb[w * 16 * HROW];
    const int nT = N_EDGES / 128;
    const int G = gridDim.x;

    int t = blockIdx.x;
    int jm = t * 128 + w * 16 + col;
    int sv = ssrc[jm], tv = sdst[jm];

    for (; t < nT; ) {
        // this tile's fragment gathers (6 independent 16B loads, L2-cached)
        short8 af[6];
        af[0] = *(const short8*)&h16[(size_t)sv * 64 + q * 8];
        af[1] = *(const short8*)&h16[(size_t)sv * 64 + 32 + q * 8];
        af[2] = *(const short8*)&h16[(size_t)tv * 64 + q * 8];
        af[3] = *(const short8*)&h16[(size_t)tv * 64 + 32 + q * 8];
        af[4] = *(const short8*)&e_sorted[(size_t)jm * 64 + q * 8];
        af[5] = *(const short8*)&e_sorted[(size_t)jm * 64 + 32 + q * 8];

        // prefetch NEXT tile's indices only (3 regs; hides idx->gather hop)
        const int tn = t + G;
        int svn = sv, tvn = tv, jn = jm;
        if (tn < nT) {
            jn = tn * 128 + w * 16 + col;
            svn = ssrc[jn]; tvn = sdst[jn];
        }

        // ---- layer 1: K=192 ----
        #pragma unroll
        for (int nt = 0; nt < 4; ++nt) {
            f32x4 acc = {0.f, 0.f, 0.f, 0.f};
            #pragma unroll
            for (int ks = 0; ks < 6; ++ks)
                acc = MFMA16(af[ks], *(const short8*)&w0s[(ks * 4 + nt) * 512 + lane * 8], acc);
            const float bv = biasS[nt * 16 + col];
            #pragma unroll
            for (int r = 0; r < 4; ++r)
                hw[(q * 4 + r) * HROW + nt * 16 + col] = f2b(fmaxf(acc[r] + bv, 0.f));
        }
        // ---- layers 2..4: K=64 ----
        #pragma unroll
        for (int li = 0; li < 3; ++li) {
            const short8 ah0 = *(const short8*)&hw[col * HROW + q * 8];
            const short8 ah1 = *(const short8*)&hw[col * HROW + 32 + q * 8];
            const u16* wls = &w1s[li * 4096];
            #pragma unroll
            for (int nt = 0; nt < 4; ++nt) {
                f32x4 acc = {0.f, 0.f, 0.f, 0.f};
                acc = MFMA16(ah0, *(const short8*)&wls[nt * 512 + lane * 8], acc);
                acc = MFMA16(ah1, *(const short8*)&wls[(4 + nt) * 512 + lane * 8], acc);
                const float bv = biasS[(li + 1) * 64 + nt * 16 + col];
                #pragma unroll
                for (int r = 0; r < 4; ++r)
                    hw[(q * 4 + r) * HROW + nt * 16 + col] = f2b(fmaxf(acc[r] + bv, 0.f));
            }
        }
        // ---- coalesced e_sorted store ----
        {
            const int erow = lane >> 2, echk = lane & 3;
            const short8 o0 = *(const short8*)&hw[erow * HROW + echk * 8];
            const short8 o1 = *(const short8*)&hw[erow * HROW + 32 + echk * 8];
            const size_t ebo = (size_t)(t * 128 + w * 16 + erow) * 64;
            *(short8*)&e_sorted[ebo + echk * 8] = o0;
            *(short8*)&e_sorted[ebo + 32 + echk * 8] = o1;
        }
        t = tn; jm = jn; sv = svn; tv = tvn;
    }
}

// ===================== segmented aggregation over sorted e-stream ============
// lane = column; wave walks contiguous rows; wave-uniform segment flush.
__global__ __launch_bounds__(256, 8)
void seg_agg(const u16* __restrict__ e_sorted, const int* __restrict__ sdst,
             float* __restrict__ agg)
{
    const int gw = (blockIdx.x * 256 + threadIdx.x) >> 6;   // global wave id
    const int lane = threadIdx.x & 63;
    const int CH = (N_EDGES + 4095) / 4096;                  // rows per wave
    int j = gw * CH;
    const int j1 = (j + CH < N_EDGES) ? j + CH : N_EDGES;
    if (j >= j1) return;
    int cur = sdst[j];
    float acc = 0.f;
    for (; j + 8 <= j1; j += 8) {
        float v[8]; int n[8];
        #pragma unroll
        for (int i = 0; i < 8; ++i) {
            v[i] = b2f(e_sorted[(size_t)(j + i) * 64 + lane]);
            n[i] = sdst[j + i];
        }
        #pragma unroll
        for (int i = 0; i < 8; ++i) {
            if (n[i] != cur) {
                atomicAdd(&agg[(size_t)cur * 64 + lane], acc);
                acc = 0.f; cur = n[i];
            }
            acc += v[i];
        }
    }
    for (; j < j1; ++j) {
        const int n = sdst[j];
        const float v = b2f(e_sorted[(size_t)j * 64 + lane]);
        if (n != cur) {
            atomicAdd(&agg[(size_t)cur * 64 + lane], acc);
            acc = 0.f; cur = n;
        }
        acc += v;
    }
    atomicAdd(&agg[(size_t)cur * 64 + lane], acc);
}

// ===================== node MLP (MFMA, reads agg fp32 directly) ==============
__global__ __launch_bounds__(512, 4)
void node_mlp(const float* __restrict__ agg,
              const u16* __restrict__ h16,
              const u16* __restrict__ wz,
              const float* __restrict__ b0, const float* __restrict__ b1,
              const float* __restrict__ b2, const float* __restrict__ b3,
              u16* __restrict__ hout16, float* __restrict__ hout32)
{
    __shared__ u16 w0s[4 * 2048];      // 16 KB
    __shared__ u16 w1s[3 * 2 * 2048];  // 24 KB
    __shared__ float biasS[256];
    __shared__ u16 hb[8 * 16 * HROW];

    const int tid = threadIdx.x;
    {
        const uint4* s = (const uint4*)wz;
        uint4* dA = (uint4*)w0s; uint4* dB = (uint4*)w1s;
        #pragma unroll
        for (int i = 0; i < 2; ++i) dA[tid + i * 512] = s[tid + i * 512];
        #pragma unroll
        for (int i = 0; i < 3; ++i) dB[tid + i * 512] = s[1024 + tid + i * 512];
        if (tid < 256) {
            const int which = tid >> 6, j = tid & 63;
            const float* bp = (which == 0) ? b0 : (which == 1) ? b1 : (which == 2) ? b2 : b3;
            biasS[tid] = bp[j];
        }
    }
    __syncthreads();

    const int w = tid >> 6, lane = tid & 63, col = lane & 15, q = lane >> 4;
    u16* hw = &hb[w * 16 * HROW];
    const int base = blockIdx.x * 128 + w * 16;

    const int nm = base + col;
    const int nmc = (nm < N_NODES) ? nm : 0;
    short8 af[4];
    af[0] = cvt8(&agg[(size_t)nmc * 64 + q * 8]);
    af[1] = cvt8(&agg[(size_t)nmc * 64 + 32 + q * 8]);
    af[2] = *(const short8*)&h16[(size_t)nmc * 64 + q * 8];
    af[3] = *(const short8*)&h16[(size_t)nmc * 64 + 32 + q * 8];

    // ---- layer 1: K=128 ----
    #pragma unroll
    for (int nt = 0; nt < 4; ++nt) {
        f32x4 c = {0.f, 0.f, 0.f, 0.f};
        #pragma unroll
        for (int ks = 0; ks < 4; ++ks)
            c = MFMA16(af[ks], *(const short8*)&w0s[(ks * 4 + nt) * 512 + lane * 8], c);
        const float bv = biasS[nt * 16 + col];
        #pragma unroll
        for (int r = 0; r < 4; ++r)
            hw[(q * 4 + r) * HROW + nt * 16 + col] = f2b(fmaxf(c[r] + bv, 0.f));
    }
    // ---- layers 2..4 ----
    #pragma unroll
    for (int li = 0; li < 3; ++li) {
        const short8 ah0 = *(const short8*)&hw[col * HROW + q * 8];
        const short8 ah1 = *(const short8*)&hw[col * HROW + 32 + q * 8];
        const u16* wls = &w1s[li * 4096];
        #pragma unroll
        for (int nt = 0; nt < 4; ++nt) {
            f32x4 c = {0.f, 0.f, 0.f, 0.f};
            c = MFMA16(ah0, *(const short8*)&wls[nt * 512 + lane * 8], c);
            c = MFMA16(ah1, *(const short8*)&wls[(4 + nt) * 512 + lane * 8], c);
            const float bv = biasS[(li + 1) * 64 + nt * 16 + col];
            #pragma unroll
            for (int r = 0; r < 4; ++r) {
                const float v = fmaxf(c[r] + bv, 0.f);
                if (li == 2 && hout32) {
                    const int row = base + q * 4 + r;
                    if (row < N_NODES) hout32[(size_t)row * 64 + nt * 16 + col] = v;
                } else {
                    hw[(q * 4 + r) * HROW + nt * 16 + col] = f2b(v);
                }
            }
        }
    }
    if (!hout32) {
        const int erow = lane >> 2, echk = lane & 3;
        const int row = base + erow;
        if (row < N_NODES) {
            const short8 o0 = *(const short8*)&hw[erow * HROW + echk * 8];
            const short8 o1 = *(const short8*)&hw[erow * HROW + 32 + echk * 8];
            *(short8*)&hout16[(size_t)row * 64 + echk * 8] = o0;
            *(short8*)&hout16[(size_t)row * 64 + 32 + echk * 8] = o1;
        }
    }
}

extern "C" void kernel_launch(void* const* d_in, const int* in_sizes, int n_in,
                              void* d_out, int out_size, void* d_ws, size_t ws_size,
                              hipStream_t stream)
{
    const float* node_h = (const float*)d_in[0];
    const float* edge_h = (const float*)d_in[1];
    const int* src      = (const int*)d_in[2];
    const int* dst      = (const int*)d_in[3];
    const float* eW[4] = {(const float*)d_in[4],  (const float*)d_in[8],
                          (const float*)d_in[12], (const float*)d_in[16]};
    const float* eb[4] = {(const float*)d_in[5],  (const float*)d_in[9],
                          (const float*)d_in[13], (const float*)d_in[17]};
    const float* nW[4] = {(const float*)d_in[6],  (const float*)d_in[10],
                          (const float*)d_in[14], (const float*)d_in[18]};
    const float* nb[4] = {(const float*)d_in[7],  (const float*)d_in[11],
                          (const float*)d_in[15], (const float*)d_in[19]};

    // ws layout
    u16* ebuf   = (u16*)d_ws;                            // e_sorted: 51.2M u16
    u16* hbuf   = ebuf + (size_t)N_EDGES * 64;           // 3.2M u16
    float* agg  = (float*)(hbuf + (size_t)N_NODES * 64); // 3.2M f32
    u16* eswz   = (u16*)(agg + (size_t)N_NODES * 64);    // 73728 u16
    u16* nswz   = eswz + 3 * 24576;                      // 61440 u16
    int* off    = (int*)(nswz + 3 * 20480);              // N+1
    int* cur    = off + (N_NODES + 4);
    int* deg    = cur + N_NODES;
    int* eidx   = deg + N_NODES;                         // E
    int* ssrc   = eidx + N_EDGES;                        // E
    int* sdst   = ssrc + N_EDGES;                        // E

    // one-time per launch
    cvt_bf16<<<(N_NODES * 64 / 8 + 255) / 256, 256, 0, stream>>>(node_h, hbuf, N_NODES * 64 / 8);
    hipMemsetAsync(deg, 0, N_NODES * sizeof(int), stream);
    csr_hist<<<(N_EDGES + 255) / 256, 256, 0, stream>>>(dst, deg);
    csr_scan<<<1, 1024, 0, stream>>>(deg, off, cur);
    csr_scatter<<<(N_EDGES + 255) / 256, 256, 0, stream>>>(src, dst, cur, eidx, ssrc, sdst);
    perm_edge<<<(N_EDGES * 8 + 255) / 256, 256, 0, stream>>>(edge_h, eidx, ebuf);
    swizzle_all<<<528, 256, 0, stream>>>(eW[0], eW[1], eW[2], eW[3],
                                         nW[0], nW[1], nW[2], nW[3], eswz, nswz);

    for (int l = 0; l < 3; ++l) {
        edge_pass<<<512, 512, 0, stream>>>(
            hbuf, ebuf, ssrc, sdst, eswz + (size_t)l * 24576,
            eb[0] + l * 64, eb[1] + l * 64, eb[2] + l * 64, eb[3] + l * 64);
        hipMemsetAsync(agg, 0, (size_t)N_NODES * 64 * sizeof(float), stream);
        seg_agg<<<1024, 256, 0, stream>>>(ebuf, sdst, agg);
        node_mlp<<<(N_NODES + 127) / 128, 512, 0, stream>>>(
            agg, hbuf, nswz + (size_t)l * 20480,
            nb[0] + l * 64, nb[1] + l * 64, nb[2] + l * 64, nb[3] + l * 64,
            (l < 2) ? hbuf : nullptr, (l == 2) ? (float*)d_out : nullptr);
    }
}

// Round 9
// 822.409 us; speedup vs baseline: 1.5928x; 1.4522x over previous
//
#include <hip/hip_runtime.h>

#define N_NODES 50000
#define N_EDGES 800000
#define HROW 72   // u16 row stride for LDS H tiles

typedef unsigned short u16;
typedef __attribute__((ext_vector_type(8))) short short8;
typedef __attribute__((ext_vector_type(4))) float f32x4;

#define MFMA16(a, b, c) __builtin_amdgcn_mfma_f32_16x16x32_bf16((a), (b), (c), 0, 0, 0)

__device__ __forceinline__ float b2f(u16 u) {
    union { unsigned int i; float f; } v; v.i = ((unsigned int)u) << 16; return v.f;
}
__device__ __forceinline__ u16 f2b(float f) {
    union { float f; unsigned int i; } v; v.f = f;
    unsigned int x = v.i;
    return (u16)((x + 0x7fffu + ((x >> 16) & 1u)) >> 16);
}
__device__ __forceinline__ short8 cvt8(const float* p) {
    const float4 a = *(const float4*)p;
    const float4 b = *(const float4*)(p + 4);
    short8 r;
    r[0] = (short)f2b(a.x); r[1] = (short)f2b(a.y); r[2] = (short)f2b(a.z); r[3] = (short)f2b(a.w);
    r[4] = (short)f2b(b.x); r[5] = (short)f2b(b.y); r[6] = (short)f2b(b.z); r[7] = (short)f2b(b.w);
    return r;
}

// ---- setup: fp32->bf16 node convert + dst histogram (merged) ----------------
__global__ void setup_cvt_hist(const float* __restrict__ node_h, u16* __restrict__ hbuf,
                               const int* __restrict__ dst, int* __restrict__ deg) {
    const int i = blockIdx.x * 256 + threadIdx.x;
    if (i < N_EDGES) atomicAdd(&deg[dst[i]], 1);
    if (i < N_NODES * 8) *(short8*)&hbuf[i * 8] = cvt8(&node_h[i * 8]);
}
__global__ void csr_scan(const int* __restrict__ deg, int* __restrict__ off,
                         int* __restrict__ cur) {
    __shared__ int tot[1024];
    const int t = threadIdx.x;
    const int beg = t * 49;
    const int end = (beg + 49 < N_NODES) ? beg + 49 : N_NODES;
    int s = 0;
    for (int i = beg; i < end; ++i) s += deg[i];
    tot[t] = s;
    __syncthreads();
    for (int d = 1; d < 1024; d <<= 1) {
        const int v = (t >= d) ? tot[t - d] : 0;
        __syncthreads();
        tot[t] += v;
        __syncthreads();
    }
    int run = tot[t] - s;
    for (int i = beg; i < end; ++i) { const int d = deg[i]; off[i] = run; cur[i] = run; run += d; }
    if (t == 1023) off[N_NODES] = tot[1023];
}
__global__ void csr_scatter(const int* __restrict__ src, const int* __restrict__ dst,
                            int* __restrict__ cur, int* __restrict__ eidx,
                            int* __restrict__ ssrc, int* __restrict__ sdst) {
    const int e = blockIdx.x * 256 + threadIdx.x;
    if (e < N_EDGES) {
        const int d = dst[e];
        const int p = atomicAdd(&cur[d], 1);
        eidx[p] = e; ssrc[p] = src[e]; sdst[p] = d;
    }
}
// permute fp32 edge features into sorted bf16 rows
__global__ void perm_edge(const float* __restrict__ eh, const int* __restrict__ eidx,
                          u16* __restrict__ out) {
    const int idx = blockIdx.x * 256 + threadIdx.x;  // one thread per 8 cols
    if (idx < N_EDGES * 8) {
        const int j = idx >> 3, c = (idx & 7) * 8;
        const int e = eidx[j];
        *(short8*)&out[(size_t)j * 64 + c] = cvt8(&eh[(size_t)e * 64 + c]);
    }
}

// ---- one-shot weight swizzle (all layers, edge + node) into B-frag order ----
__global__ void swizzle_all(const float* __restrict__ eW0, const float* __restrict__ eW1,
                            const float* __restrict__ eW2, const float* __restrict__ eW3,
                            const float* __restrict__ nW0, const float* __restrict__ nW1,
                            const float* __restrict__ nW2, const float* __restrict__ nW3,
                            u16* __restrict__ eswz, u16* __restrict__ nswz)
{
    const int ETOT = 3 * 12 * 2048, NTOT = 3 * 10 * 2048;
    for (int idx = blockIdx.x * 256 + threadIdx.x; idx < ETOT + NTOT; idx += gridDim.x * 256) {
        const bool isE = idx < ETOT;
        const int id = isE ? idx : idx - ETOT;
        const int per = isE ? 12 * 2048 : 10 * 2048;
        const int l = id / per, rem = id % per;
        const int t = rem >> 11;
        const int r2 = rem & 2047;
        const int nt = r2 >> 9, lane = (r2 >> 3) & 63, j = r2 & 7;
        const int ks0 = isE ? 6 : 4;
        const float* W; int ks;
        if (t < ks0) {
            W = (isE ? eW0 : nW0) + (size_t)l * (isE ? 192 * 64 : 128 * 64);
            ks = t;
        } else {
            const int u = t - ks0;
            const float* Wb = isE ? (u < 2 ? eW1 : (u < 4 ? eW2 : eW3))
                                  : (u < 2 ? nW1 : (u < 4 ? nW2 : nW3));
            W = Wb + (size_t)l * 4096; ks = u & 1;
        }
        const int k = ks * 32 + (lane >> 4) * 8 + j;
        const int n = nt * 16 + (lane & 15);
        const u16 v = f2b(W[k * 64 + n]);
        if (isE) eswz[id] = v; else nswz[id] = v;
    }
}

// ===================== edge pass + fused dst aggregation =====================
// 512 thr = 8 waves; wave owns 16 sorted-edge rows per tile of 128.
// After the MLP, each wave segment-reduces its 16 rows (dst-sorted) and
// flushes ~2 coalesced atomicAdd rows into agg.
__global__ __launch_bounds__(512, 4)
void edge_pass(const u16* __restrict__ h16,
               u16* __restrict__ e_sorted,            // bf16 state, in-place
               const int* __restrict__ ssrc, const int* __restrict__ sdst,
               const u16* __restrict__ wz,
               const float* __restrict__ b0, const float* __restrict__ b1,
               const float* __restrict__ b2, const float* __restrict__ b3,
               float* __restrict__ agg)
{
    __shared__ u16 w0s[6 * 2048];      // 24 KB
    __shared__ u16 w1s[3 * 2 * 2048];  // 24 KB
    __shared__ float biasS[256];
    __shared__ u16 hb[8 * 16 * HROW];  // 18 KB
    __shared__ int dstS[8][16];        // per-wave dst of the 16 tile rows

    const int tid = threadIdx.x;
    {
        const uint4* s = (const uint4*)wz;
        uint4* dA = (uint4*)w0s; uint4* dB = (uint4*)w1s;
        #pragma unroll
        for (int i = 0; i < 3; ++i) dA[tid + i * 512] = s[tid + i * 512];
        #pragma unroll
        for (int i = 0; i < 3; ++i) dB[tid + i * 512] = s[1536 + tid + i * 512];
        if (tid < 256) {
            const int which = tid >> 6, j = tid & 63;
            const float* bp = (which == 0) ? b0 : (which == 1) ? b1 : (which == 2) ? b2 : b3;
            biasS[tid] = bp[j];
        }
    }
    __syncthreads();  // only barrier

    const int w = tid >> 6, lane = tid & 63, col = lane & 15, q = lane >> 4;
    u16* hw = &hb[w * 16 * HROW];
    const int nT = N_EDGES / 128;
    const int G = gridDim.x;

    // prologue: tile t fragments + tile t+G indices
    int t = blockIdx.x;
    int j0 = t * 128 + w * 16 + col;
    int sv0 = ssrc[j0], tv0 = sdst[j0];
    short8 af[6];
    af[0] = *(const short8*)&h16[(size_t)sv0 * 64 + q * 8];
    af[1] = *(const short8*)&h16[(size_t)sv0 * 64 + 32 + q * 8];
    af[2] = *(const short8*)&h16[(size_t)tv0 * 64 + q * 8];
    af[3] = *(const short8*)&h16[(size_t)tv0 * 64 + 32 + q * 8];
    af[4] = *(const short8*)&e_sorted[(size_t)j0 * 64 + q * 8];
    af[5] = *(const short8*)&e_sorted[(size_t)j0 * 64 + 32 + q * 8];
    int t1 = t + G, j1 = 0, sv1 = 0, tv1 = 0;
    if (t1 < nT) { j1 = t1 * 128 + w * 16 + col; sv1 = ssrc[j1]; tv1 = sdst[j1]; }

    for (; t < nT; ) {
        // prefetch next tile's fragments (indices loaded last iteration)
        short8 afn[6];
        if (t1 < nT) {
            afn[0] = *(const short8*)&h16[(size_t)sv1 * 64 + q * 8];
            afn[1] = *(const short8*)&h16[(size_t)sv1 * 64 + 32 + q * 8];
            afn[2] = *(const short8*)&h16[(size_t)tv1 * 64 + q * 8];
            afn[3] = *(const short8*)&h16[(size_t)tv1 * 64 + 32 + q * 8];
            afn[4] = *(const short8*)&e_sorted[(size_t)j1 * 64 + q * 8];
            afn[5] = *(const short8*)&e_sorted[(size_t)j1 * 64 + 32 + q * 8];
        }
        // prefetch indices two tiles ahead
        const int t2 = t1 + G;
        int j2 = 0, sv2 = 0, tv2 = 0;
        if (t2 < nT) { j2 = t2 * 128 + w * 16 + col; sv2 = ssrc[j2]; tv2 = sdst[j2]; }

        // publish this tile's dst list for the fused reduce (wave-private LDS)
        if (q == 0) dstS[w][col] = tv0;

        // ---- layer 1: K=192 ----
        #pragma unroll
        for (int nt = 0; nt < 4; ++nt) {
            f32x4 acc = {0.f, 0.f, 0.f, 0.f};
            #pragma unroll
            for (int ks = 0; ks < 6; ++ks)
                acc = MFMA16(af[ks], *(const short8*)&w0s[(ks * 4 + nt) * 512 + lane * 8], acc);
            const float bv = biasS[nt * 16 + col];
            #pragma unroll
            for (int r = 0; r < 4; ++r)
                hw[(q * 4 + r) * HROW + nt * 16 + col] = f2b(fmaxf(acc[r] + bv, 0.f));
        }
        // ---- layers 2..4: K=64 ----
        #pragma unroll
        for (int li = 0; li < 3; ++li) {
            const short8 ah0 = *(const short8*)&hw[col * HROW + q * 8];
            const short8 ah1 = *(const short8*)&hw[col * HROW + 32 + q * 8];
            const u16* wls = &w1s[li * 4096];
            #pragma unroll
            for (int nt = 0; nt < 4; ++nt) {
                f32x4 acc = {0.f, 0.f, 0.f, 0.f};
                acc = MFMA16(ah0, *(const short8*)&wls[nt * 512 + lane * 8], acc);
                acc = MFMA16(ah1, *(const short8*)&wls[(4 + nt) * 512 + lane * 8], acc);
                const float bv = biasS[(li + 1) * 64 + nt * 16 + col];
                #pragma unroll
                for (int r = 0; r < 4; ++r)
                    hw[(q * 4 + r) * HROW + nt * 16 + col] = f2b(fmaxf(acc[r] + bv, 0.f));
            }
        }
        // ---- coalesced e_sorted store ----
        {
            const int erow = lane >> 2, echk = lane & 3;
            const short8 o0 = *(const short8*)&hw[erow * HROW + echk * 8];
            const short8 o1 = *(const short8*)&hw[erow * HROW + 32 + echk * 8];
            const size_t ebo = (size_t)(t * 128 + w * 16 + erow) * 64;
            *(short8*)&e_sorted[ebo + echk * 8] = o0;
            *(short8*)&e_sorted[ebo + 32 + echk * 8] = o1;
        }
        // ---- fused segmented reduce: lane = column, walk 16 dst-sorted rows --
        {
            float racc = 0.f;
            int curd = dstS[w][0];
            #pragma unroll
            for (int r = 0; r < 16; ++r) {
                const float v = b2f(hw[r * HROW + lane]);
                const int d = dstS[w][r];        // wave-uniform broadcast
                if (d != curd) {                 // wave-uniform branch
                    atomicAdd(&agg[(size_t)curd * 64 + lane], racc);
                    racc = 0.f; curd = d;
                }
                racc += v;
            }
            atomicAdd(&agg[(size_t)curd * 64 + lane], racc);
        }
        // rotate pipeline
        #pragma unroll
        for (int i = 0; i < 6; ++i) af[i] = afn[i];
        t = t1; t1 = t2;
        j0 = j1; sv0 = sv1; tv0 = tv1;
        j1 = j2; sv1 = sv2; tv1 = tv2;
    }
}

// ===================== node MLP (MFMA; reads agg fp32, then zeroes it) =======
__global__ __launch_bounds__(512, 4)
void node_mlp(float* __restrict__ agg,
              const u16* __restrict__ h16,
              const u16* __restrict__ wz,
              const float* __restrict__ b0, const float* __restrict__ b1,
              const float* __restrict__ b2, const float* __restrict__ b3,
              u16* __restrict__ hout16, float* __restrict__ hout32)
{
    __shared__ u16 w0s[4 * 2048];      // 16 KB
    __shared__ u16 w1s[3 * 2 * 2048];  // 24 KB
    __shared__ float biasS[256];
    __shared__ u16 hb[8 * 16 * HROW];

    const int tid = threadIdx.x;
    {
        const uint4* s = (const uint4*)wz;
        uint4* dA = (uint4*)w0s; uint4* dB = (uint4*)w1s;
        #pragma unroll
        for (int i = 0; i < 2; ++i) dA[tid + i * 512] = s[tid + i * 512];
        #pragma unroll
        for (int i = 0; i < 3; ++i) dB[tid + i * 512] = s[1024 + tid + i * 512];
        if (tid < 256) {
            const int which = tid >> 6, j = tid & 63;
            const float* bp = (which == 0) ? b0 : (which == 1) ? b1 : (which == 2) ? b2 : b3;
            biasS[tid] = bp[j];
        }
    }
    __syncthreads();

    const int w = tid >> 6, lane = tid & 63, col = lane & 15, q = lane >> 4;
    u16* hw = &hb[w * 16 * HROW];
    const int base = blockIdx.x * 128 + w * 16;

    const int nm = base + col;
    const int nmc = (nm < N_NODES) ? nm : 0;
    short8 af[4];
    af[0] = cvt8(&agg[(size_t)nmc * 64 + q * 8]);
    af[1] = cvt8(&agg[(size_t)nmc * 64 + 32 + q * 8]);
    af[2] = *(const short8*)&h16[(size_t)nmc * 64 + q * 8];
    af[3] = *(const short8*)&h16[(size_t)nmc * 64 + 32 + q * 8];

    // zero agg (for the next layer's atomics); only valid rows (avoid clamp race)
    if (nm < N_NODES) {
        const float4 z = {0.f, 0.f, 0.f, 0.f};
        *(float4*)&agg[(size_t)nm * 64 + q * 8]      = z;
        *(float4*)&agg[(size_t)nm * 64 + q * 8 + 4]  = z;
        *(float4*)&agg[(size_t)nm * 64 + 32 + q * 8]     = z;
        *(float4*)&agg[(size_t)nm * 64 + 32 + q * 8 + 4] = z;
    }

    // ---- layer 1: K=128 ----
    #pragma unroll
    for (int nt = 0; nt < 4; ++nt) {
        f32x4 c = {0.f, 0.f, 0.f, 0.f};
        #pragma unroll
        for (int ks = 0; ks < 4; ++ks)
            c = MFMA16(af[ks], *(const short8*)&w0s[(ks * 4 + nt) * 512 + lane * 8], c);
        const float bv = biasS[nt * 16 + col];
        #pragma unroll
        for (int r = 0; r < 4; ++r)
            hw[(q * 4 + r) * HROW + nt * 16 + col] = f2b(fmaxf(c[r] + bv, 0.f));
    }
    // ---- layers 2..4 ----
    #pragma unroll
    for (int li = 0; li < 3; ++li) {
        const short8 ah0 = *(const short8*)&hw[col * HROW + q * 8];
        const short8 ah1 = *(const short8*)&hw[col * HROW + 32 + q * 8];
        const u16* wls = &w1s[li * 4096];
        #pragma unroll
        for (int nt = 0; nt < 4; ++nt) {
            f32x4 c = {0.f, 0.f, 0.f, 0.f};
            c = MFMA16(ah0, *(const short8*)&wls[nt * 512 + lane * 8], c);
            c = MFMA16(ah1, *(const short8*)&wls[(4 + nt) * 512 + lane * 8], c);
            const float bv = biasS[(li + 1) * 64 + nt * 16 + col];
            #pragma unroll
            for (int r = 0; r < 4; ++r) {
                const float v = fmaxf(c[r] + bv, 0.f);
                if (li == 2 && hout32) {
                    const int row = base + q * 4 + r;
                    if (row < N_NODES) hout32[(size_t)row * 64 + nt * 16 + col] = v;
                } else {
                    hw[(q * 4 + r) * HROW + nt * 16 + col] = f2b(v);
                }
            }
        }
    }
    if (!hout32) {
        const int erow = lane >> 2, echk = lane & 3;
        const int row = base + erow;
        if (row < N_NODES) {
            const short8 o0 = *(const short8*)&hw[erow * HROW + echk * 8];
            const short8 o1 = *(const short8*)&hw[erow * HROW + 32 + echk * 8];
            *(short8*)&hout16[(size_t)row * 64 + echk * 8] = o0;
            *(short8*)&hout16[(size_t)row * 64 + 32 + echk * 8] = o1;
        }
    }
}

extern "C" void kernel_launch(void* const* d_in, const int* in_sizes, int n_in,
                              void* d_out, int out_size, void* d_ws, size_t ws_size,
                              hipStream_t stream)
{
    const float* node_h = (const float*)d_in[0];
    const float* edge_h = (const float*)d_in[1];
    const int* src      = (const int*)d_in[2];
    const int* dst      = (const int*)d_in[3];
    const float* eW[4] = {(const float*)d_in[4],  (const float*)d_in[8],
                          (const float*)d_in[12], (const float*)d_in[16]};
    const float* eb[4] = {(const float*)d_in[5],  (const float*)d_in[9],
                          (const float*)d_in[13], (const float*)d_in[17]};
    const float* nW[4] = {(const float*)d_in[6],  (const float*)d_in[10],
                          (const float*)d_in[14], (const float*)d_in[18]};
    const float* nb[4] = {(const float*)d_in[7],  (const float*)d_in[11],
                          (const float*)d_in[15], (const float*)d_in[19]};

    // ws layout
    u16* ebuf   = (u16*)d_ws;                            // e_sorted: 51.2M u16
    u16* hbuf   = ebuf + (size_t)N_EDGES * 64;           // 3.2M u16
    float* agg  = (float*)(hbuf + (size_t)N_NODES * 64); // 3.2M f32
    u16* eswz   = (u16*)(agg + (size_t)N_NODES * 64);    // 73728 u16
    u16* nswz   = eswz + 3 * 24576;                      // 61440 u16
    int* off    = (int*)(nswz + 3 * 20480);              // N+1
    int* cur    = off + (N_NODES + 4);
    int* deg    = cur + N_NODES;
    int* eidx   = deg + N_NODES;                         // E
    int* ssrc   = eidx + N_EDGES;                        // E
    int* sdst   = ssrc + N_EDGES;                        // E

    // one-time per launch
    hipMemsetAsync(deg, 0, N_NODES * sizeof(int), stream);
    hipMemsetAsync(agg, 0, (size_t)N_NODES * 64 * sizeof(float), stream);
    setup_cvt_hist<<<(N_EDGES + 255) / 256, 256, 0, stream>>>(node_h, hbuf, dst, deg);
    csr_scan<<<1, 1024, 0, stream>>>(deg, off, cur);
    csr_scatter<<<(N_EDGES + 255) / 256, 256, 0, stream>>>(src, dst, cur, eidx, ssrc, sdst);
    perm_edge<<<(N_EDGES * 8 + 255) / 256, 256, 0, stream>>>(edge_h, eidx, ebuf);
    swizzle_all<<<528, 256, 0, stream>>>(eW[0], eW[1], eW[2], eW[3],
                                         nW[0], nW[1], nW[2], nW[3], eswz, nswz);

    for (int l = 0; l < 3; ++l) {
        edge_pass<<<512, 512, 0, stream>>>(
            hbuf, ebuf, ssrc, sdst, eswz + (size_t)l * 24576,
            eb[0] + l * 64, eb[1] + l * 64, eb[2] + l * 64, eb[3] + l * 64, agg);
        node_mlp<<<(N_NODES + 127) / 128, 512, 0, stream>>>(
            agg, hbuf, nswz + (size_t)l * 20480,
            nb[0] + l * 64, nb[1] + l * 64, nb[2] + l * 64, nb[3] + l * 64,
            (l < 2) ? hbuf : nullptr, (l == 2) ? (float*)d_out : nullptr);
    }
}